// Round 1
// baseline (432.984 us; speedup 1.0000x reference)
//
#include <hip/hip_runtime.h>

// LIF neuron forward: x [B=16, C=64, T=16, H=64, W=64] f32, decay (1,) f32.
//   mem   = mem_old * sigmoid(decay) * (1 - spike) + x_t
//   spike = (mem > 0.5) ? 1 : 0
// out = spikes (clip(0,1) is identity on {0,1}).
//
// Round 2 changes vs round 1:
//  - Software-pipelined 8+8 load schedule: only 8 float4 loads live at a
//    time (32 VGPRs vs 64). Iteration t of the first compute loop consumes
//    xa[t] and immediately reissues the load of t+8 into the same slot.
//    Target: VGPR ~90 -> ~60, occupancy 5 -> 8 waves/SIMD (HW cap), smoother
//    read-stream issue. Per-wave MLP stays 8-deep; TLP nearly doubles.
//  - Arithmetic chain UNCHANGED (bit-exact vs JAX ref: __fmul_rn/__fadd_rn,
//    precise expf). Spike threshold at 0.5 means 1-ulp drift can flip
//    outputs; do not enable contraction.
//  - NT load/store hints unchanged (both streams touch-once).

#define T_STEPS 16
#define HW      4096            // H*W
#define BC      1024            // B*C
#define S4      1024            // HW/4 float4 columns per (b,c)

typedef float f4 __attribute__((ext_vector_type(4)));

__global__ __launch_bounds__(256) void
lif_fwd_kernel(const float* __restrict__ x,
               const float* __restrict__ decay,
               float* __restrict__ out) {
    const unsigned tid = blockIdx.x * blockDim.x + threadIdx.x;  // [0, BC*S4)
    const unsigned bc  = tid >> 10;
    const unsigned s4  = tid & (S4 - 1);
    const unsigned base = bc * (T_STEPS * HW) + s4 * 4;          // element offset

    const float d  = decay[0];
    const float ds = 1.0f / (1.0f + expf(-d));

    // Prologue: first 8 loads in flight (32 VGPRs of load buffer).
    f4 xa[8];
#pragma unroll
    for (int t = 0; t < 8; ++t) {
        xa[t] = __builtin_nontemporal_load(
            reinterpret_cast<const f4*>(x + base + (unsigned)t * HW));
    }

    float mx = 0.f, my = 0.f, mz = 0.f, mw = 0.f;
    float sx = 0.f, sy = 0.f, sz = 0.f, sw = 0.f;

#define LIF_STEP(XV, TIDX)                                                   \
    do {                                                                     \
        mx = __fadd_rn(__fmul_rn(__fmul_rn(mx, ds), 1.0f - sx), (XV).x);     \
        my = __fadd_rn(__fmul_rn(__fmul_rn(my, ds), 1.0f - sy), (XV).y);     \
        mz = __fadd_rn(__fmul_rn(__fmul_rn(mz, ds), 1.0f - sz), (XV).z);     \
        mw = __fadd_rn(__fmul_rn(__fmul_rn(mw, ds), 1.0f - sw), (XV).w);     \
        sx = (mx > 0.5f) ? 1.0f : 0.0f;                                      \
        sy = (my > 0.5f) ? 1.0f : 0.0f;                                      \
        sz = (mz > 0.5f) ? 1.0f : 0.0f;                                      \
        sw = (mw > 0.5f) ? 1.0f : 0.0f;                                      \
        f4 ov;                                                               \
        ov.x = sx; ov.y = sy; ov.z = sz; ov.w = sw;                          \
        __builtin_nontemporal_store(ov,                                      \
            reinterpret_cast<f4*>(out + base + (unsigned)(TIDX) * HW));      \
    } while (0)

    // Steady state: consume xa[t], refill the same slot with load of t+8.
#pragma unroll
    for (int t = 0; t < 8; ++t) {
        f4 xv = xa[t];
        xa[t] = __builtin_nontemporal_load(
            reinterpret_cast<const f4*>(x + base + (unsigned)(t + 8) * HW));
        LIF_STEP(xv, t);
    }

    // Epilogue: drain the second batch.
#pragma unroll
    for (int t = 8; t < 16; ++t) {
        f4 xv = xa[t - 8];
        LIF_STEP(xv, t);
    }

#undef LIF_STEP
}

extern "C" void kernel_launch(void* const* d_in, const int* in_sizes, int n_in,
                              void* d_out, int out_size, void* d_ws, size_t ws_size,
                              hipStream_t stream) {
    const float* x     = (const float*)d_in[0];
    const float* decay = (const float*)d_in[1];
    float*       out   = (float*)d_out;

    const int block = 256;
    const int grid  = (BC * S4) / block;   // 4096 blocks
    lif_fwd_kernel<<<grid, block, 0, stream>>>(x, decay, out);
}